// Round 8
// baseline (238.555 us; speedup 1.0000x reference)
//
#include <hip/hip_runtime.h>
#include <hip/hip_bf16.h>

#define NF     32
#define ED     128
#define NBATCH 2048
#define NPAIRS 496
#define BM     128
#define NITER  (NBATCH / BM)   // 16 M-blocks per pair

typedef __attribute__((ext_vector_type(8))) short short8;   // 8 bf16 = 16 B (MFMA A/B frag)
typedef __attribute__((ext_vector_type(4))) short short4v;  // 4 bf16 = 8 B
typedef __attribute__((ext_vector_type(4))) float f32x4;

#define FEMB_BF_ELEMS ((size_t)NF * NBATCH * ED)            // 8,388,608
#define W_BF_ELEMS    ((size_t)NPAIRS * ED * ED)            // 8,126,464
#define WS_NEEDED     ((FEMB_BF_ELEMS + W_BF_ELEMS) * 2)    // ~33 MB

__device__ __forceinline__ short f2bf(float x) {
    union { __hip_bfloat16 b; short s; } v;
    v.b = __float2bfloat16(x);
    return v.s;
}
__device__ __forceinline__ float bf2f(short s) {
    union { unsigned int u; float f; } v;
    v.u = ((unsigned int)(unsigned short)s) << 16;
    return v.f;
}

// ---------- Pre-pass 1: femb fp32 [b][f][d] -> bf16 field-major [f][b][d] ----------
__global__ __launch_bounds__(256)
void prep_femb(const float* __restrict__ femb, unsigned short* __restrict__ fb) {
    int n = blockIdx.x * 256 + threadIdx.x;       // 1,048,576 threads x 8 elems
    int d8 = n & 15;
    int b  = (n >> 4) & (NBATCH - 1);
    int f  = n >> 15;
    const float* s = femb + ((size_t)b * NF + f) * ED + d8 * 8;
    f32x4 lo = __builtin_nontemporal_load(reinterpret_cast<const f32x4*>(s));
    f32x4 hi = __builtin_nontemporal_load(reinterpret_cast<const f32x4*>(s + 4));
    short8 pk;
    pk[0]=f2bf(lo.x); pk[1]=f2bf(lo.y); pk[2]=f2bf(lo.z); pk[3]=f2bf(lo.w);
    pk[4]=f2bf(hi.x); pk[5]=f2bf(hi.y); pk[6]=f2bf(hi.z); pk[7]=f2bf(hi.w);
    *reinterpret_cast<short8*>(fb + ((size_t)f * NBATCH + b) * ED + d8 * 8) = pk;
}

// ---------- Pre-pass 2: W fp32 -> bf16 flat [p][e][d] ----------
__global__ __launch_bounds__(256)
void prep_w(const float* __restrict__ W, unsigned short* __restrict__ wb) {
    size_t n = (size_t)blockIdx.x * 256 + threadIdx.x;
    size_t idx8 = n * 8;
    if (idx8 >= W_BF_ELEMS) return;
    const float* s = W + idx8;
    f32x4 lo = __builtin_nontemporal_load(reinterpret_cast<const f32x4*>(s));
    f32x4 hi = __builtin_nontemporal_load(reinterpret_cast<const f32x4*>(s + 4));
    short8 pk;
    pk[0]=f2bf(lo.x); pk[1]=f2bf(lo.y); pk[2]=f2bf(lo.z); pk[3]=f2bf(lo.w);
    pk[4]=f2bf(hi.x); pk[5]=f2bf(hi.y); pk[6]=f2bf(hi.z); pk[7]=f2bf(hi.w);
    *reinterpret_cast<short8*>(wb + idx8) = pk;
}

// ---------- Main kernel: NO LDS, NO barriers ----------
// Grid: 992 blocks = 496 pairs x 2 batch-halves. 256 threads = 4 waves,
// one e-quadrant (32 rows of W) per wave. W fragments live in registers
// for all 16 iterations; vi/vj fragments load straight from the bf16
// field-major planes (L2-served, 4x intra-block redundancy absorbed).
// No __syncthreads => no vmcnt(0) store-queue drains; NT stores stream.
__global__ __launch_bounds__(256, 4)
void bilinear_noshared(const unsigned short* __restrict__ fb,
                       const unsigned short* __restrict__ wb,
                       float* __restrict__ out)
{
    const int bid  = blockIdx.x;
    const int p    = bid >> 1;          // pair 0..495
    const int half = bid & 1;           // batch half 0..1 (64 rows each per M-block)

    // pair -> (fi, fj) per lexicographic combinations(range(32), 2)
    int fi = 0, rem = p;
    while (rem >= NF - 1 - fi) { rem -= NF - 1 - fi; ++fi; }
    const int fj = fi + 1 + rem;

    const int t    = threadIdx.x;       // 0..255
    const int lane = t & 63;
    const int we   = t >> 6;            // wave = e-quadrant 0..3
    const int lhi  = lane >> 4;         // 0..3
    const int llo  = lane & 15;         // 0..15

    const unsigned short* fiPlane = fb + (size_t)fi * NBATCH * ED;
    const unsigned short* fjPlane = fb + (size_t)fj * NBATCH * ED;
    const unsigned short* wp      = wb + (size_t)p * (ED * ED);

    // ---- W fragments -> registers, once (A-operand of MFMA) ----
    // aW[mi][kk]: e = we*32 + mi*16 + llo, k = kk*32 + lhi*8 .. +7
    short8 aW[2][4];
    #pragma unroll
    for (int mi = 0; mi < 2; ++mi) {
        int e = we * 32 + mi * 16 + llo;
        #pragma unroll
        for (int kk = 0; kk < 4; ++kk)
            aW[mi][kk] = *reinterpret_cast<const short8*>(
                wp + (size_t)e * ED + kk * 32 + lhi * 8);
    }

    for (int mb = 0; mb < NITER; ++mb) {
        const int bbase = mb * BM + half * 64;

        // ---- vj fragments (epilogue operand) — issue early, used late ----
        short4v vjr[4][2];
        #pragma unroll
        for (int ni = 0; ni < 4; ++ni) {
            const unsigned short* vj = fjPlane + (size_t)(bbase + ni * 16 + llo) * ED;
            #pragma unroll
            for (int mi = 0; mi < 2; ++mi)
                vjr[ni][mi] = *reinterpret_cast<const short4v*>(
                    vj + we * 32 + mi * 16 + lhi * 4);
        }

        // ---- Compute: D[e][b] = W . vi^T, vi frags straight from global ----
        f32x4 acc[2][4] = {};
        #pragma unroll
        for (int kk = 0; kk < 4; ++kk) {
            short8 bv[4];
            #pragma unroll
            for (int ni = 0; ni < 4; ++ni)
                bv[ni] = *reinterpret_cast<const short8*>(
                    fiPlane + (size_t)(bbase + ni * 16 + llo) * ED + kk * 32 + lhi * 8);
            #pragma unroll
            for (int mi = 0; mi < 2; ++mi)
                #pragma unroll
                for (int ni = 0; ni < 4; ++ni)
                    acc[mi][ni] = __builtin_amdgcn_mfma_f32_16x16x32_bf16(
                        aW[mi][kk], bv[ni], acc[mi][ni], 0, 0, 0);
        }

        // ---- Epilogue: out[b][p][e] = D[e][b] * vj[e], NT stores ----
        // D frag: row(e-local) = lhi*4 + q, col(b-local) = llo
        #pragma unroll
        for (int ni = 0; ni < 4; ++ni) {
            int b = bbase + ni * 16 + llo;
            float* op = out + ((size_t)b * NPAIRS + p) * ED;
            #pragma unroll
            for (int mi = 0; mi < 2; ++mi) {
                int e0 = we * 32 + mi * 16 + lhi * 4;
                short4v vs = vjr[ni][mi];
                f32x4 r = acc[mi][ni];
                f32x4 o;
                o.x = r[0] * bf2f(vs[0]); o.y = r[1] * bf2f(vs[1]);
                o.z = r[2] * bf2f(vs[2]); o.w = r[3] * bf2f(vs[3]);
                __builtin_nontemporal_store(o, reinterpret_cast<f32x4*>(op + e0));
            }
        }
    }
}

// ---------- Fallback (fp32 inputs, LDS path) if ws too small ----------
__global__ __launch_bounds__(512, 2)
void bilinear_f32(const float* __restrict__ femb,
                  const float* __restrict__ W,
                  float* __restrict__ out)
{
    __shared__ unsigned char ldsW[128 * 256];
    __shared__ unsigned char ldsA[128 * 256];

    const int p = blockIdx.x;
    int fi = 0, rem = p;
    while (rem >= NF - 1 - fi) { rem -= NF - 1 - fi; ++fi; }
    const int fj = fi + 1 + rem;

    const int t    = threadIdx.x;
    const int lane = t & 63;
    const int wave = t >> 6;

    {
        const float* wp = W + (size_t)p * (ED * ED);
        #pragma unroll
        for (int it = 0; it < 4; ++it) {
            int idx8 = it * 4096 + t * 8;
            int e = idx8 >> 7, d = idx8 & 127;
            const float* s = wp + (size_t)e * ED + d;
            f32x4 lo = __builtin_nontemporal_load(reinterpret_cast<const f32x4*>(s));
            f32x4 hi = __builtin_nontemporal_load(reinterpret_cast<const f32x4*>(s + 4));
            short8 pk;
            pk[0]=f2bf(lo.x); pk[1]=f2bf(lo.y); pk[2]=f2bf(lo.z); pk[3]=f2bf(lo.w);
            pk[4]=f2bf(hi.x); pk[5]=f2bf(hi.y); pk[6]=f2bf(hi.z); pk[7]=f2bf(hi.w);
            *reinterpret_cast<short8*>(ldsW + e * 256 + ((d * 2) ^ ((e & 15) << 4))) = pk;
        }
    }

    const int r_ = t >> 4;
    const int d_ = (t * 8) & 127;
    const size_t ROWSTRIDE32 = (size_t)32 * NF * ED;

    const int we  = wave & 3;
    const int wb_ = wave >> 2;
    const int lhi = lane >> 4;
    const int llo = lane & 15;

    f32x4 stg[8];
    {
        const float* base = femb + ((size_t)r_ * NF + fi) * ED + d_;
        #pragma unroll
        for (int q = 0; q < 4; ++q) {
            const float* s = base + (size_t)q * ROWSTRIDE32;
            stg[2*q]   = *reinterpret_cast<const f32x4*>(s);
            stg[2*q+1] = *reinterpret_cast<const f32x4*>(s + 4);
        }
    }

    for (int mb = 0; mb < NITER; ++mb) {
        const int b0 = mb * BM;
        #pragma unroll
        for (int q = 0; q < 4; ++q) {
            int r = r_ + q * 32;
            f32x4 lo = stg[2*q], hi = stg[2*q+1];
            short8 pk;
            pk[0]=f2bf(lo.x); pk[1]=f2bf(lo.y); pk[2]=f2bf(lo.z); pk[3]=f2bf(lo.w);
            pk[4]=f2bf(hi.x); pk[5]=f2bf(hi.y); pk[6]=f2bf(hi.z); pk[7]=f2bf(hi.w);
            *reinterpret_cast<short8*>(ldsA + r * 256 + ((d_ * 2) ^ ((r & 15) << 4))) = pk;
        }
        __syncthreads();

        if (mb + 1 < NITER) {
            const float* base = femb + ((size_t)((mb + 1) * BM + r_) * NF + fi) * ED + d_;
            #pragma unroll
            for (int q = 0; q < 4; ++q) {
                const float* s = base + (size_t)q * ROWSTRIDE32;
                stg[2*q]   = *reinterpret_cast<const f32x4*>(s);
                stg[2*q+1] = *reinterpret_cast<const f32x4*>(s + 4);
            }
        }

        f32x4 vjr[4][2];
        #pragma unroll
        for (int ni = 0; ni < 4; ++ni) {
            int b = b0 + wb_ * 64 + ni * 16 + llo;
            const float* vj = femb + ((size_t)b * NF + fj) * ED;
            #pragma unroll
            for (int mi = 0; mi < 2; ++mi) {
                int e0 = we * 32 + mi * 16 + lhi * 4;
                vjr[ni][mi] = *reinterpret_cast<const f32x4*>(vj + e0);
            }
        }

        f32x4 acc[2][4] = {};
        #pragma unroll
        for (int kk = 0; kk < 4; ++kk) {
            const int db = kk * 64 + lhi * 16;
            short8 a[2], b[4];
            #pragma unroll
            for (int mi = 0; mi < 2; ++mi) {
                int e = we * 32 + mi * 16 + llo;
                a[mi] = *reinterpret_cast<const short8*>(ldsW + e * 256 + (db ^ (llo << 4)));
            }
            #pragma unroll
            for (int ni = 0; ni < 4; ++ni) {
                int r = wb_ * 64 + ni * 16 + llo;
                b[ni] = *reinterpret_cast<const short8*>(ldsA + r * 256 + (db ^ (llo << 4)));
            }
            #pragma unroll
            for (int mi = 0; mi < 2; ++mi)
                #pragma unroll
                for (int ni = 0; ni < 4; ++ni)
                    acc[mi][ni] = __builtin_amdgcn_mfma_f32_16x16x32_bf16(a[mi], b[ni], acc[mi][ni], 0, 0, 0);
        }
        __syncthreads();

        #pragma unroll
        for (int ni = 0; ni < 4; ++ni) {
            int b = b0 + wb_ * 64 + ni * 16 + llo;
            float* op = out + ((size_t)b * NPAIRS + p) * ED;
            #pragma unroll
            for (int mi = 0; mi < 2; ++mi) {
                int e0 = we * 32 + mi * 16 + lhi * 4;
                f32x4 v = vjr[ni][mi];
                f32x4 r = acc[mi][ni];
                f32x4 o;
                o.x = r[0] * v.x; o.y = r[1] * v.y;
                o.z = r[2] * v.z; o.w = r[3] * v.w;
                __builtin_nontemporal_store(o, reinterpret_cast<f32x4*>(op + e0));
            }
        }
    }
}

extern "C" void kernel_launch(void* const* d_in, const int* in_sizes, int n_in,
                              void* d_out, int out_size, void* d_ws, size_t ws_size,
                              hipStream_t stream) {
    (void)in_sizes; (void)n_in; (void)out_size;
    const float* femb = (const float*)d_in[0];
    const float* W    = (const float*)d_in[1];
    float* out        = (float*)d_out;

    if (ws_size >= WS_NEEDED) {
        unsigned short* fbp = (unsigned short*)d_ws;
        unsigned short* wbp = fbp + FEMB_BF_ELEMS;
        hipLaunchKernelGGL(prep_femb, dim3(FEMB_BF_ELEMS / 8 / 256), dim3(256), 0, stream, femb, fbp);
        hipLaunchKernelGGL(prep_w,    dim3((W_BF_ELEMS / 8 + 255) / 256), dim3(256), 0, stream, W, wbp);
        hipLaunchKernelGGL(bilinear_noshared, dim3(NPAIRS * 2), dim3(256), 0, stream, fbp, wbp, out);
    } else {
        hipLaunchKernelGGL(bilinear_f32, dim3(NPAIRS), dim3(512), 0, stream, femb, W, out);
    }
}

// Round 9
// 213.659 us; speedup vs baseline: 1.1165x; 1.1165x over previous
//
#include <hip/hip_runtime.h>
#include <hip/hip_bf16.h>

#define NF     32
#define ED     128
#define NBATCH 2048
#define NPAIRS 496
#define BM     128            // M-chunk rows per block
#define NMC    (NBATCH/BM)    // 16 M-chunks
#define NGRP   136            // pair-groups: chunks of <=4 consecutive pairs within an fi band
#define NWG    (NGRP*NMC)     // 2176 blocks

typedef __attribute__((ext_vector_type(8))) short short8;   // 8 bf16 = 16 B
typedef __attribute__((ext_vector_type(4))) short short4v;  // 4 bf16 = 8 B
typedef __attribute__((ext_vector_type(4))) float f32x4;

#define FEMB_BF_ELEMS ((size_t)NF * NBATCH * ED)            // 8,388,608
#define W_BF_ELEMS    ((size_t)NPAIRS * ED * ED)            // 8,126,464
#define WS_NEEDED     ((FEMB_BF_ELEMS + W_BF_ELEMS) * 2)    // ~33 MB

__device__ __forceinline__ short f2bf(float x) {
    union { __hip_bfloat16 b; short s; } v;
    v.b = __float2bfloat16(x);
    return v.s;
}
__device__ __forceinline__ float bf2f(short s) {
    union { unsigned int u; float f; } v;
    v.u = ((unsigned int)(unsigned short)s) << 16;
    return v.f;
}

// ---------- Pre-pass 1: femb fp32 [b][f][d] -> bf16 field-major [f][b][d] ----------
__global__ __launch_bounds__(256)
void prep_femb(const float* __restrict__ femb, unsigned short* __restrict__ fb) {
    int n = blockIdx.x * 256 + threadIdx.x;       // 1,048,576 threads x 8 elems
    int d8 = n & 15;
    int b  = (n >> 4) & (NBATCH - 1);
    int f  = n >> 15;
    const float* s = femb + ((size_t)b * NF + f) * ED + d8 * 8;
    f32x4 lo = __builtin_nontemporal_load(reinterpret_cast<const f32x4*>(s));
    f32x4 hi = __builtin_nontemporal_load(reinterpret_cast<const f32x4*>(s + 4));
    short8 pk;
    pk[0]=f2bf(lo.x); pk[1]=f2bf(lo.y); pk[2]=f2bf(lo.z); pk[3]=f2bf(lo.w);
    pk[4]=f2bf(hi.x); pk[5]=f2bf(hi.y); pk[6]=f2bf(hi.z); pk[7]=f2bf(hi.w);
    *reinterpret_cast<short8*>(fb + ((size_t)f * NBATCH + b) * ED + d8 * 8) = pk;
}

// ---------- Pre-pass 2: W fp32 [p][e][d] -> bf16 FRAGMENT-MAJOR ----------
// Layout: wswz[p][etile(8)][kk(4)][lane(64)][8 bf16]. A wave loads its MFMA
// A-fragment (e = etile*16 + (lane&15), d = kk*32 + (lane>>4)*8 ..+7) as ONE
// fully-coalesced 1KB global_load_dwordx4 (16B per lane, lane-linear).
__global__ __launch_bounds__(256)
void prep_w_swz(const float* __restrict__ W, unsigned short* __restrict__ wswz) {
    int n = blockIdx.x * 256 + threadIdx.x;       // 496*2048 = 1,015,808 threads
    int lane  = n & 63;
    int kk    = (n >> 6) & 3;
    int etile = (n >> 8) & 7;
    int p     = n >> 11;
    int e  = etile * 16 + (lane & 15);
    int d0 = kk * 32 + (lane >> 4) * 8;
    const float* s = W + (size_t)p * (ED * ED) + (size_t)e * ED + d0;
    f32x4 lo = __builtin_nontemporal_load(reinterpret_cast<const f32x4*>(s));
    f32x4 hi = __builtin_nontemporal_load(reinterpret_cast<const f32x4*>(s + 4));
    short8 pk;
    pk[0]=f2bf(lo.x); pk[1]=f2bf(lo.y); pk[2]=f2bf(lo.z); pk[3]=f2bf(lo.w);
    pk[4]=f2bf(hi.x); pk[5]=f2bf(hi.y); pk[6]=f2bf(hi.z); pk[7]=f2bf(hi.w);
    *reinterpret_cast<short8*>(wswz + (size_t)n * 8) = pk;
}

// ---------- Main kernel: 4-consecutive-pair groups, one M-chunk per block ----------
// Block = (group g, M-chunk mc). Group = up to 4 consecutive pairs sharing fi
// (lexicographic band). vi tile staged once in LDS (32KB, swizzled), shared by
// all pairs; W fragments load coalesced from wswz (L2-hot: group's 16 M-chunk
// blocks are XCD-adjacent); per b-row the 4 pairs write 2KB CONTIGUOUS output.
__global__ __launch_bounds__(512, 4)
void bilinear_grp(const unsigned short* __restrict__ fb,
                  const unsigned short* __restrict__ wswz,
                  float* __restrict__ out)
{
    __shared__ unsigned char ldsA[128 * 256];   // vi tile [r][d] bf16, swizzled

    // XCD-chunked bijective swizzle (NWG % 8 == 0): each XCD gets 272
    // consecutive wg = 17 whole groups -> W slices + vi planes L2-hot.
    int bid = blockIdx.x;
    int wg  = (bid & 7) * (NWG / 8) + (bid >> 3);
    int g   = wg >> 4;          // group 0..135
    int mc  = wg & 15;          // M-chunk 0..15

    // ---- decode group -> (fi, j0, cnt); heavy-first: 112 full-4, then 24 tails ----
    int fi = 0, j0, cnt;
    if (g < 112) {
        int rem = g;
        for (;;) { int nf = (31 - fi) >> 2; if (rem < nf) break; rem -= nf; ++fi; }
        j0 = fi + 1 + rem * 4; cnt = 4;
    } else {
        int rem = g - 112;
        for (;;) {
            int r = (31 - fi) & 3;
            if (r > 0) { if (rem == 0) { cnt = r; break; } --rem; }
            ++fi;
        }
        j0 = fi + 1 + ((31 - fi) >> 2) * 4;
    }
    // pair index of (fi, j0): p0 = sum_{k<fi}(31-k) + (j0-fi-1)
    const int p0 = 31 * fi - (fi * (fi - 1)) / 2 + (j0 - fi - 1);

    const int t    = threadIdx.x;     // 0..511
    const int lane = t & 63;
    const int wave = t >> 6;          // 0..7
    const int we   = wave & 3;        // e-quadrant (32 rows)
    const int wb_  = wave >> 2;       // b-half (64 cols)
    const int lhi  = lane >> 4;
    const int llo  = lane & 15;
    const int b0   = mc * BM;

    // ---- Stage vi tile: fb[fi][b0+r][d] -> swizzled LDS ----
    const unsigned short* fiP = fb + (size_t)fi * NBATCH * ED;
    #pragma unroll
    for (int it = 0; it < 4; ++it) {
        int idx8 = it * 4096 + t * 8;
        int r = idx8 >> 7, d = idx8 & 127;
        short8 v = *reinterpret_cast<const short8*>(fiP + (size_t)(b0 + r) * ED + d);
        *reinterpret_cast<short8*>(ldsA + r * 256 + ((d * 2) ^ ((r & 15) << 4))) = v;
    }
    __syncthreads();   // the ONLY barrier

    for (int pr = 0; pr < cnt; ++pr) {
        const int p  = p0 + pr;
        const int fj = j0 + pr;
        const unsigned short* fjP = fb + (size_t)fj * NBATCH * ED;
        const unsigned short* wp  = wswz + (size_t)p * (ED * ED);

        // vj fragments for epilogue (8B/lane, L2/L3-served)
        short4v vjr[4][2];
        #pragma unroll
        for (int ni = 0; ni < 4; ++ni) {
            const unsigned short* vj = fjP + (size_t)(b0 + wb_ * 64 + ni * 16 + llo) * ED;
            #pragma unroll
            for (int mi = 0; mi < 2; ++mi)
                vjr[ni][mi] = *reinterpret_cast<const short4v*>(
                    vj + we * 32 + mi * 16 + lhi * 4);
        }

        // ---- Compute: D[e][b] = W . vi^T ----
        f32x4 acc[2][4] = {};
        #pragma unroll
        for (int kk = 0; kk < 4; ++kk) {
            short8 a[2], b[4];
            #pragma unroll
            for (int mi = 0; mi < 2; ++mi) {
                int etile = we * 2 + mi;
                a[mi] = *reinterpret_cast<const short8*>(
                    wp + ((size_t)(etile * 4 + kk) * 64 + lane) * 8);   // coalesced 1KB/wave
            }
            const int db = kk * 64 + lhi * 16;
            #pragma unroll
            for (int ni = 0; ni < 4; ++ni) {
                int r = wb_ * 64 + ni * 16 + llo;
                b[ni] = *reinterpret_cast<const short8*>(ldsA + r * 256 + (db ^ (llo << 4)));
            }
            #pragma unroll
            for (int mi = 0; mi < 2; ++mi)
                #pragma unroll
                for (int ni = 0; ni < 4; ++ni)
                    acc[mi][ni] = __builtin_amdgcn_mfma_f32_16x16x32_bf16(
                        a[mi], b[ni], acc[mi][ni], 0, 0, 0);
        }

        // ---- Epilogue: out[b][p][e] = D[e][b] * vj[e], NT float4 stores ----
        // Across the pr-loop, row b's columns p0..p0+3 are written temporally
        // adjacent -> 2KB contiguous spans per row instead of 512B scatter.
        #pragma unroll
        for (int ni = 0; ni < 4; ++ni) {
            int b = b0 + wb_ * 64 + ni * 16 + llo;
            float* op = out + ((size_t)b * NPAIRS + p) * ED;
            #pragma unroll
            for (int mi = 0; mi < 2; ++mi) {
                int e0 = we * 32 + mi * 16 + lhi * 4;
                short4v vs = vjr[ni][mi];
                f32x4 r = acc[mi][ni];
                f32x4 o;
                o.x = r[0] * bf2f(vs[0]); o.y = r[1] * bf2f(vs[1]);
                o.z = r[2] * bf2f(vs[2]); o.w = r[3] * bf2f(vs[3]);
                __builtin_nontemporal_store(o, reinterpret_cast<f32x4*>(op + e0));
            }
        }
    }
}

// ---------- Fallback (fp32 inputs, LDS path) if ws too small ----------
__global__ __launch_bounds__(512, 2)
void bilinear_f32(const float* __restrict__ femb,
                  const float* __restrict__ W,
                  float* __restrict__ out)
{
    __shared__ unsigned char ldsW[128 * 256];
    __shared__ unsigned char ldsA[128 * 256];

    const int p = blockIdx.x;
    int fi = 0, rem = p;
    while (rem >= NF - 1 - fi) { rem -= NF - 1 - fi; ++fi; }
    const int fj = fi + 1 + rem;

    const int t    = threadIdx.x;
    const int lane = t & 63;
    const int wave = t >> 6;

    {
        const float* wp = W + (size_t)p * (ED * ED);
        #pragma unroll
        for (int it = 0; it < 4; ++it) {
            int idx8 = it * 4096 + t * 8;
            int e = idx8 >> 7, d = idx8 & 127;
            const float* s = wp + (size_t)e * ED + d;
            f32x4 lo = __builtin_nontemporal_load(reinterpret_cast<const f32x4*>(s));
            f32x4 hi = __builtin_nontemporal_load(reinterpret_cast<const f32x4*>(s + 4));
            short8 pk;
            pk[0]=f2bf(lo.x); pk[1]=f2bf(lo.y); pk[2]=f2bf(lo.z); pk[3]=f2bf(lo.w);
            pk[4]=f2bf(hi.x); pk[5]=f2bf(hi.y); pk[6]=f2bf(hi.z); pk[7]=f2bf(hi.w);
            *reinterpret_cast<short8*>(ldsW + e * 256 + ((d * 2) ^ ((e & 15) << 4))) = pk;
        }
    }

    const int r_ = t >> 4;
    const int d_ = (t * 8) & 127;
    const size_t ROWSTRIDE32 = (size_t)32 * NF * ED;

    const int we  = wave & 3;
    const int wb_ = wave >> 2;
    const int lhi = lane >> 4;
    const int llo = lane & 15;

    f32x4 stg[8];
    {
        const float* base = femb + ((size_t)r_ * NF + fi) * ED + d_;
        #pragma unroll
        for (int q = 0; q < 4; ++q) {
            const float* s = base + (size_t)q * ROWSTRIDE32;
            stg[2*q]   = *reinterpret_cast<const f32x4*>(s);
            stg[2*q+1] = *reinterpret_cast<const f32x4*>(s + 4);
        }
    }

    for (int mb = 0; mb < NBATCH / BM; ++mb) {
        const int b0 = mb * BM;
        #pragma unroll
        for (int q = 0; q < 4; ++q) {
            int r = r_ + q * 32;
            f32x4 lo = stg[2*q], hi = stg[2*q+1];
            short8 pk;
            pk[0]=f2bf(lo.x); pk[1]=f2bf(lo.y); pk[2]=f2bf(lo.z); pk[3]=f2bf(lo.w);
            pk[4]=f2bf(hi.x); pk[5]=f2bf(hi.y); pk[6]=f2bf(hi.z); pk[7]=f2bf(hi.w);
            *reinterpret_cast<short8*>(ldsA + r * 256 + ((d_ * 2) ^ ((r & 15) << 4))) = pk;
        }
        __syncthreads();

        if (mb + 1 < NBATCH / BM) {
            const float* base = femb + ((size_t)((mb + 1) * BM + r_) * NF + fi) * ED + d_;
            #pragma unroll
            for (int q = 0; q < 4; ++q) {
                const float* s = base + (size_t)q * ROWSTRIDE32;
                stg[2*q]   = *reinterpret_cast<const f32x4*>(s);
                stg[2*q+1] = *reinterpret_cast<const f32x4*>(s + 4);
            }
        }

        f32x4 vjr[4][2];
        #pragma unroll
        for (int ni = 0; ni < 4; ++ni) {
            int b = b0 + wb_ * 64 + ni * 16 + llo;
            const float* vj = femb + ((size_t)b * NF + fj) * ED;
            #pragma unroll
            for (int mi = 0; mi < 2; ++mi) {
                int e0 = we * 32 + mi * 16 + lhi * 4;
                vjr[ni][mi] = *reinterpret_cast<const f32x4*>(vj + e0);
            }
        }

        f32x4 acc[2][4] = {};
        #pragma unroll
        for (int kk = 0; kk < 4; ++kk) {
            const int db = kk * 64 + lhi * 16;
            short8 a[2], b[4];
            #pragma unroll
            for (int mi = 0; mi < 2; ++mi) {
                int e = we * 32 + mi * 16 + llo;
                a[mi] = *reinterpret_cast<const short8*>(ldsW + e * 256 + (db ^ (llo << 4)));
            }
            #pragma unroll
            for (int ni = 0; ni < 4; ++ni) {
                int r = wb_ * 64 + ni * 16 + llo;
                b[ni] = *reinterpret_cast<const short8*>(ldsA + r * 256 + (db ^ (llo << 4)));
            }
            #pragma unroll
            for (int mi = 0; mi < 2; ++mi)
                #pragma unroll
                for (int ni = 0; ni < 4; ++ni)
                    acc[mi][ni] = __builtin_amdgcn_mfma_f32_16x16x32_bf16(a[mi], b[ni], acc[mi][ni], 0, 0, 0);
        }
        __syncthreads();

        #pragma unroll
        for (int ni = 0; ni < 4; ++ni) {
            int b = b0 + wb_ * 64 + ni * 16 + llo;
            float* op = out + ((size_t)b * NPAIRS + p) * ED;
            #pragma unroll
            for (int mi = 0; mi < 2; ++mi) {
                int e0 = we * 32 + mi * 16 + lhi * 4;
                f32x4 v = vjr[ni][mi];
                f32x4 r = acc[mi][ni];
                f32x4 o;
                o.x = r[0] * v.x; o.y = r[1] * v.y;
                o.z = r[2] * v.z; o.w = r[3] * v.w;
                __builtin_nontemporal_store(o, reinterpret_cast<f32x4*>(op + e0));
            }
        }
    }
}

extern "C" void kernel_launch(void* const* d_in, const int* in_sizes, int n_in,
                              void* d_out, int out_size, void* d_ws, size_t ws_size,
                              hipStream_t stream) {
    (void)in_sizes; (void)n_in; (void)out_size;
    const float* femb = (const float*)d_in[0];
    const float* W    = (const float*)d_in[1];
    float* out        = (float*)d_out;

    if (ws_size >= WS_NEEDED) {
        unsigned short* fbp = (unsigned short*)d_ws;
        unsigned short* wsz = fbp + FEMB_BF_ELEMS;
        hipLaunchKernelGGL(prep_femb, dim3(FEMB_BF_ELEMS / 8 / 256), dim3(256), 0, stream, femb, fbp);
        hipLaunchKernelGGL(prep_w_swz, dim3(W_BF_ELEMS / 8 / 256), dim3(256), 0, stream, W, wsz);
        hipLaunchKernelGGL(bilinear_grp, dim3(NWG), dim3(512), 0, stream, fbp, wsz, out);
    } else {
        hipLaunchKernelGGL(bilinear_f32, dim3(NPAIRS), dim3(512), 0, stream, femb, W, out);
    }
}

// Round 10
// 178.610 us; speedup vs baseline: 1.3356x; 1.1962x over previous
//
#include <hip/hip_runtime.h>
#include <hip/hip_bf16.h>

#define NF     32
#define ED     128
#define NBATCH 2048
#define NPAIRS 496
#define BM     128
#define NITER  (NBATCH / BM)   // 16 M-blocks per pair

typedef __attribute__((ext_vector_type(8))) short short8;   // 8 bf16 (MFMA A/B frag)
typedef __attribute__((ext_vector_type(4))) short short4v;  // 4 bf16
typedef __attribute__((ext_vector_type(4))) float f32x4;

#define FEMB_BF_ELEMS ((size_t)NF * NBATCH * ED)            // 8,388,608
#define W_BF_ELEMS    ((size_t)NPAIRS * ED * ED)            // 8,126,464
#define WS_NEEDED     ((FEMB_BF_ELEMS + W_BF_ELEMS) * 2)    // ~33 MB

// LDS-only barrier: orders LDS (lgkmcnt) but does NOT drain the VMEM queue.
// __syncthreads() emits s_waitcnt vmcnt(0) before s_barrier, which forces the
// NT-store queue + prefetch loads to HBM every iteration (m97 barrier-drain).
// Our cross-iteration hazard is ONLY ldsA reuse -> lgkmcnt(0) suffices.
#define LGKM_BARRIER() asm volatile("s_waitcnt lgkmcnt(0)\n\ts_barrier" ::: "memory")

__device__ __forceinline__ short f2bf(float x) {
    union { __hip_bfloat16 b; short s; } v;
    v.b = __float2bfloat16(x);
    return v.s;
}
__device__ __forceinline__ float bf2f(short s) {
    union { unsigned int u; float f; } v;
    v.u = ((unsigned int)(unsigned short)s) << 16;
    return v.f;
}

// ---------- Pre-pass 1: femb fp32 [b][f][d] -> bf16 field-major [f][b][d] ----------
__global__ __launch_bounds__(256)
void prep_femb(const float* __restrict__ femb, unsigned short* __restrict__ fb) {
    int n = blockIdx.x * 256 + threadIdx.x;       // 1,048,576 threads x 8 elems
    int d8 = n & 15;
    int b  = (n >> 4) & (NBATCH - 1);
    int f  = n >> 15;
    const float* s = femb + ((size_t)b * NF + f) * ED + d8 * 8;
    f32x4 lo = __builtin_nontemporal_load(reinterpret_cast<const f32x4*>(s));
    f32x4 hi = __builtin_nontemporal_load(reinterpret_cast<const f32x4*>(s + 4));
    short8 pk;
    pk[0]=f2bf(lo.x); pk[1]=f2bf(lo.y); pk[2]=f2bf(lo.z); pk[3]=f2bf(lo.w);
    pk[4]=f2bf(hi.x); pk[5]=f2bf(hi.y); pk[6]=f2bf(hi.z); pk[7]=f2bf(hi.w);
    *reinterpret_cast<short8*>(fb + ((size_t)f * NBATCH + b) * ED + d8 * 8) = pk;
}

// ---------- Pre-pass 2: W fp32 -> bf16 flat [p][e][d] ----------
__global__ __launch_bounds__(256)
void prep_w(const float* __restrict__ W, unsigned short* __restrict__ wb) {
    size_t n = (size_t)blockIdx.x * 256 + threadIdx.x;
    size_t idx8 = n * 8;
    if (idx8 >= W_BF_ELEMS) return;
    const float* s = W + idx8;
    f32x4 lo = __builtin_nontemporal_load(reinterpret_cast<const f32x4*>(s));
    f32x4 hi = __builtin_nontemporal_load(reinterpret_cast<const f32x4*>(s + 4));
    short8 pk;
    pk[0]=f2bf(lo.x); pk[1]=f2bf(lo.y); pk[2]=f2bf(lo.z); pk[3]=f2bf(lo.w);
    pk[4]=f2bf(hi.x); pk[5]=f2bf(hi.y); pk[6]=f2bf(hi.z); pk[7]=f2bf(hi.w);
    *reinterpret_cast<short8*>(wb + idx8) = pk;
}

// LDS layout (both tiles): 128 rows x 256 B, swizzled:
//   byte(row, col) = row*256 + (col ^ ((row & 15) << 4))   -> conflict-free ds_read_b128

// ---------- Main kernel, bf16 inputs from ws (r7 structure + LGKM barriers) ----------
__global__ __launch_bounds__(512, 2)
void bilinear_bf16(const unsigned short* __restrict__ fb,
                   const unsigned short* __restrict__ wb,
                   float* __restrict__ out)
{
    __shared__ unsigned char ldsW[128 * 256];
    __shared__ unsigned char ldsA[128 * 256];

    const int p = blockIdx.x;
    int fi = 0, rem = p;
    while (rem >= NF - 1 - fi) { rem -= NF - 1 - fi; ++fi; }
    const int fj = fi + 1 + rem;

    const int t    = threadIdx.x;
    const int lane = t & 63;
    const int wave = t >> 6;

    // ---- Stage W once: bf16, read-once (NT), swizzled LDS write ----
    {
        const unsigned short* wp = wb + (size_t)p * (ED * ED);
        #pragma unroll
        for (int it = 0; it < 4; ++it) {
            int idx8 = it * 4096 + t * 8;
            int e = idx8 >> 7, d = idx8 & 127;
            short8 pk = __builtin_nontemporal_load(
                reinterpret_cast<const short8*>(wp + idx8));
            *reinterpret_cast<short8*>(ldsW + e * 256 + ((d * 2) ^ ((e & 15) << 4))) = pk;
        }
    }

    // vi staging coords: thread covers rows {r_, r_+32, r_+64, r_+96} at d_..d_+7
    const int r_ = t >> 4;
    const int d_ = (t * 8) & 127;
    const unsigned short* fiPlane = fb + (size_t)fi * NBATCH * ED;
    const unsigned short* fjPlane = fb + (size_t)fj * NBATCH * ED;

    const int we  = wave & 3;       // e-quadrant
    const int wb_ = wave >> 2;      // b-half
    const int lhi = lane >> 4;
    const int llo = lane & 15;

    short8 stg[4];
    #pragma unroll
    for (int q = 0; q < 4; ++q)
        stg[q] = *reinterpret_cast<const short8*>(fiPlane + (size_t)(r_ + q * 32) * ED + d_);

    for (int mb = 0; mb < NITER; ++mb) {
        const int b0 = mb * BM;

        // ---- A-write: staged bf16 -> swizzled LDS (no cvt) ----
        #pragma unroll
        for (int q = 0; q < 4; ++q) {
            int r = r_ + q * 32;
            *reinterpret_cast<short8*>(ldsA + r * 256 + ((d_ * 2) ^ ((r & 15) << 4))) = stg[q];
        }
        LGKM_BARRIER();   // A visible; VMEM (stores/prefetch) NOT drained

        // ---- Issue next vi prefetch ----
        if (mb + 1 < NITER) {
            const unsigned short* base = fiPlane + (size_t)((mb + 1) * BM + r_) * ED + d_;
            #pragma unroll
            for (int q = 0; q < 4; ++q)
                stg[q] = *reinterpret_cast<const short8*>(base + (size_t)q * 32 * ED);
        }

        // ---- Prefetch vj (bf16) for epilogue ----
        short4v vjr[4][2];
        #pragma unroll
        for (int ni = 0; ni < 4; ++ni) {
            int b = b0 + wb_ * 64 + ni * 16 + llo;
            const unsigned short* vj = fjPlane + (size_t)b * ED;
            #pragma unroll
            for (int mi = 0; mi < 2; ++mi) {
                int e0 = we * 32 + mi * 16 + lhi * 4;
                vjr[ni][mi] = *reinterpret_cast<const short4v*>(vj + e0);
            }
        }

        // ---- Compute: D[e][b] = W . vi^T ----
        f32x4 acc[2][4] = {};
        #pragma unroll
        for (int kk = 0; kk < 4; ++kk) {
            const int db = kk * 64 + lhi * 16;
            short8 a[2], b[4];
            #pragma unroll
            for (int mi = 0; mi < 2; ++mi) {
                int e = we * 32 + mi * 16 + llo;
                a[mi] = *reinterpret_cast<const short8*>(ldsW + e * 256 + (db ^ (llo << 4)));
            }
            #pragma unroll
            for (int ni = 0; ni < 4; ++ni) {
                int r = wb_ * 64 + ni * 16 + llo;
                b[ni] = *reinterpret_cast<const short8*>(ldsA + r * 256 + (db ^ (llo << 4)));
            }
            #pragma unroll
            for (int mi = 0; mi < 2; ++mi)
                #pragma unroll
                for (int ni = 0; ni < 4; ++ni)
                    acc[mi][ni] = __builtin_amdgcn_mfma_f32_16x16x32_bf16(a[mi], b[ni], acc[mi][ni], 0, 0, 0);
        }
        LGKM_BARRIER();   // all ds_reads of ldsA done -> next iter may overwrite

        // ---- Epilogue: out = D * vj, NT stores (free to pipeline across iters) ----
        #pragma unroll
        for (int ni = 0; ni < 4; ++ni) {
            int b = b0 + wb_ * 64 + ni * 16 + llo;
            float* op = out + ((size_t)b * NPAIRS + p) * ED;
            #pragma unroll
            for (int mi = 0; mi < 2; ++mi) {
                int e0 = we * 32 + mi * 16 + lhi * 4;
                short4v vs = vjr[ni][mi];
                f32x4 r = acc[mi][ni];
                f32x4 o;
                o.x = r[0] * bf2f(vs[0]); o.y = r[1] * bf2f(vs[1]);
                o.z = r[2] * bf2f(vs[2]); o.w = r[3] * bf2f(vs[3]);
                __builtin_nontemporal_store(o, reinterpret_cast<f32x4*>(op + e0));
            }
        }
    }
}

// ---------- Fallback (fp32 inputs) if ws too small ----------
__global__ __launch_bounds__(512, 2)
void bilinear_f32(const float* __restrict__ femb,
                  const float* __restrict__ W,
                  float* __restrict__ out)
{
    __shared__ unsigned char ldsW[128 * 256];
    __shared__ unsigned char ldsA[128 * 256];

    const int p = blockIdx.x;
    int fi = 0, rem = p;
    while (rem >= NF - 1 - fi) { rem -= NF - 1 - fi; ++fi; }
    const int fj = fi + 1 + rem;

    const int t    = threadIdx.x;
    const int lane = t & 63;
    const int wave = t >> 6;

    {
        const float* wp = W + (size_t)p * (ED * ED);
        #pragma unroll
        for (int it = 0; it < 4; ++it) {
            int idx8 = it * 4096 + t * 8;
            int e = idx8 >> 7, d = idx8 & 127;
            const float* s = wp + (size_t)e * ED + d;
            f32x4 lo = __builtin_nontemporal_load(reinterpret_cast<const f32x4*>(s));
            f32x4 hi = __builtin_nontemporal_load(reinterpret_cast<const f32x4*>(s + 4));
            short8 pk;
            pk[0]=f2bf(lo.x); pk[1]=f2bf(lo.y); pk[2]=f2bf(lo.z); pk[3]=f2bf(lo.w);
            pk[4]=f2bf(hi.x); pk[5]=f2bf(hi.y); pk[6]=f2bf(hi.z); pk[7]=f2bf(hi.w);
            *reinterpret_cast<short8*>(ldsW + e * 256 + ((d * 2) ^ ((e & 15) << 4))) = pk;
        }
    }

    const int r_ = t >> 4;
    const int d_ = (t * 8) & 127;
    const size_t ROWSTRIDE32 = (size_t)32 * NF * ED;

    const int we  = wave & 3;
    const int wb_ = wave >> 2;
    const int lhi = lane >> 4;
    const int llo = lane & 15;

    f32x4 stg[8];
    {
        const float* base = femb + ((size_t)r_ * NF + fi) * ED + d_;
        #pragma unroll
        for (int q = 0; q < 4; ++q) {
            const float* s = base + (size_t)q * ROWSTRIDE32;
            stg[2*q]   = *reinterpret_cast<const f32x4*>(s);
            stg[2*q+1] = *reinterpret_cast<const f32x4*>(s + 4);
        }
    }

    for (int mb = 0; mb < NITER; ++mb) {
        const int b0 = mb * BM;
        #pragma unroll
        for (int q = 0; q < 4; ++q) {
            int r = r_ + q * 32;
            f32x4 lo = stg[2*q], hi = stg[2*q+1];
            short8 pk;
            pk[0]=f2bf(lo.x); pk[1]=f2bf(lo.y); pk[2]=f2bf(lo.z); pk[3]=f2bf(lo.w);
            pk[4]=f2bf(hi.x); pk[5]=f2bf(hi.y); pk[6]=f2bf(hi.z); pk[7]=f2bf(hi.w);
            *reinterpret_cast<short8*>(ldsA + r * 256 + ((d_ * 2) ^ ((r & 15) << 4))) = pk;
        }
        __syncthreads();

        if (mb + 1 < NITER) {
            const float* base = femb + ((size_t)((mb + 1) * BM + r_) * NF + fi) * ED + d_;
            #pragma unroll
            for (int q = 0; q < 4; ++q) {
                const float* s = base + (size_t)q * ROWSTRIDE32;
                stg[2*q]   = *reinterpret_cast<const f32x4*>(s);
                stg[2*q+1] = *reinterpret_cast<const f32x4*>(s + 4);
            }
        }

        f32x4 vjr[4][2];
        #pragma unroll
        for (int ni = 0; ni < 4; ++ni) {
            int b = b0 + wb_ * 64 + ni * 16 + llo;
            const float* vj = femb + ((size_t)b * NF + fj) * ED;
            #pragma unroll
            for (int mi = 0; mi < 2; ++mi) {
                int e0 = we * 32 + mi * 16 + lhi * 4;
                vjr[ni][mi] = *reinterpret_cast<const f32x4*>(vj + e0);
            }
        }

        f32x4 acc[2][4] = {};
        #pragma unroll
        for (int kk = 0; kk < 4; ++kk) {
            const int db = kk * 64 + lhi * 16;
            short8 a[2], b[4];
            #pragma unroll
            for (int mi = 0; mi < 2; ++mi) {
                int e = we * 32 + mi * 16 + llo;
                a[mi] = *reinterpret_cast<const short8*>(ldsW + e * 256 + (db ^ (llo << 4)));
            }
            #pragma unroll
            for (int ni = 0; ni < 4; ++ni) {
                int r = wb_ * 64 + ni * 16 + llo;
                b[ni] = *reinterpret_cast<const short8*>(ldsA + r * 256 + (db ^ (llo << 4)));
            }
            #pragma unroll
            for (int mi = 0; mi < 2; ++mi)
                #pragma unroll
                for (int ni = 0; ni < 4; ++ni)
                    acc[mi][ni] = __builtin_amdgcn_mfma_f32_16x16x32_bf16(a[mi], b[ni], acc[mi][ni], 0, 0, 0);
        }
        __syncthreads();

        #pragma unroll
        for (int ni = 0; ni < 4; ++ni) {
            int b = b0 + wb_ * 64 + ni * 16 + llo;
            float* op = out + ((size_t)b * NPAIRS + p) * ED;
            #pragma unroll
            for (int mi = 0; mi < 2; ++mi) {
                int e0 = we * 32 + mi * 16 + lhi * 4;
                f32x4 v = vjr[ni][mi];
                f32x4 r = acc[mi][ni];
                f32x4 o;
                o.x = r[0] * v.x; o.y = r[1] * v.y;
                o.z = r[2] * v.z; o.w = r[3] * v.w;
                __builtin_nontemporal_store(o, reinterpret_cast<f32x4*>(op + e0));
            }
        }
    }
}

extern "C" void kernel_launch(void* const* d_in, const int* in_sizes, int n_in,
                              void* d_out, int out_size, void* d_ws, size_t ws_size,
                              hipStream_t stream) {
    (void)in_sizes; (void)n_in; (void)out_size;
    const float* femb = (const float*)d_in[0];
    const float* W    = (const float*)d_in[1];
    float* out        = (float*)d_out;

    if (ws_size >= WS_NEEDED) {
        unsigned short* fbp = (unsigned short*)d_ws;
        unsigned short* wbp = fbp + FEMB_BF_ELEMS;
        hipLaunchKernelGGL(prep_femb, dim3(FEMB_BF_ELEMS / 8 / 256), dim3(256), 0, stream, femb, fbp);
        hipLaunchKernelGGL(prep_w,    dim3((W_BF_ELEMS / 8 + 255) / 256), dim3(256), 0, stream, W, wbp);
        hipLaunchKernelGGL(bilinear_bf16, dim3(NPAIRS), dim3(512), 0, stream, fbp, wbp, out);
    } else {
        hipLaunchKernelGGL(bilinear_f32, dim3(NPAIRS), dim3(512), 0, stream, femb, W, out);
    }
}